// Round 4
// baseline (560.939 us; speedup 1.0000x reference)
//
#include <hip/hip_runtime.h>
#include <math.h>

// ---------------- constants ----------------
constexpr float DLO[8] = {-0.010597401784997278f, 0.032883011666982945f, 0.030841381835986965f,
                          -0.18703481171888114f, -0.02798376941698385f, 0.6308807679295904f,
                          0.7148465705525415f, 0.23037781330885523f};
constexpr float DHI[8] = {-0.23037781330885523f, 0.7148465705525415f, -0.6308807679295904f,
                          -0.02798376941698385f, 0.18703481171888114f, 0.030841381835986965f,
                          -0.032883011666982945f, -0.010597401784997278f};

// cos/sin(2*pi*m/21), m=0..20 — compile-time tables (replaces libm sincosf)
constexpr float CT21[21] = {
  1.0f,          0.95557281f,  0.82623877f,  0.62348980f,  0.36534102f,  0.07473009f,
  -0.22252093f, -0.5f,        -0.73305187f, -0.90096887f, -0.98883083f,
  -0.98883083f, -0.90096887f, -0.73305187f, -0.5f,        -0.22252093f,
  0.07473009f,   0.36534102f,  0.62348980f,  0.82623877f,  0.95557281f};
constexpr float ST21[21] = {
  0.0f,          0.29475517f,  0.56332006f,  0.78183148f,  0.93087375f,  0.99720380f,
  0.97492791f,   0.86602540f,  0.68017274f,  0.43388374f,  0.14904227f,
  -0.14904227f, -0.43388374f, -0.68017274f, -0.86602540f, -0.97492791f,
  -0.99720380f, -0.93087375f, -0.78183148f, -0.56332006f, -0.29475517f};

// dwt, mode='symmetric' with pywt phase: left pad 6, right pad 7
// out[i] = sum_j xe[2i+j] * filt[7-j]
template<int N>
__device__ __forceinline__ void dwt_step(const float* in, float* a, float* d) {
  constexpr int NO = (N + 7) / 2;
#pragma unroll
  for (int i = 0; i < NO; i++) {
    float sa = 0.f, sd = 0.f;
#pragma unroll
    for (int j = 0; j < 8; j++) {
      int rel = 2 * i + j - 6;
      int idx = (rel < 0) ? (-rel - 1) : ((rel >= N) ? (2 * N - rel - 1) : rel);
      float v = in[idx];
      sa = fmaf(v, DLO[7 - j], sa);
      sd = fmaf(v, DHI[7 - j], sd);
    }
    a[i] = sa;
    d[i] = sd;
  }
}

// ---------------- kernel 1: features ----------------
// combined[b][row][s], rows: 0..20 x, 21..31 |rfft|, 32..38 cA4, 39..45 cD4,
// 46..53 cD3, 54..63 cD2, 64..77 cD1
__global__ __launch_bounds__(256) void features_kernel(const float* __restrict__ x,
                                                       float* __restrict__ comb) {
  __shared__ float xl[256 * 21];
  const int tid = threadIdx.x;
  const int g0 = blockIdx.x * 256;
  for (int idx = tid; idx < 256 * 21; idx += 256) xl[idx] = x[g0 * 21 + idx];
  __syncthreads();

  const int gid = g0 + tid;
  const int b = gid >> 10, s = gid & 1023;

  float xx[21];
#pragma unroll
  for (int t = 0; t < 21; t++) xx[t] = xl[tid * 21 + t];

  float* cb = comb + ((b * 78) << 10) + s;

  // raw copy
#pragma unroll
  for (int t = 0; t < 21; t++) cb[t << 10] = xx[t];

  // 21-point DFT magnitudes (k = 0..10), trig from constexpr tables
#pragma unroll
  for (int k = 0; k < 11; k++) {
    float re = 0.f, im = 0.f;
#pragma unroll
    for (int t = 0; t < 21; t++) {
      constexpr int M = 21;
      const int m = (k * t) % M;  // compile-time under unroll
      re = fmaf(xx[t], CT21[m], re);
      im = fmaf(xx[t], ST21[m], im);
    }
    cb[(21 + k) << 10] = sqrtf(re * re + im * im);
  }

  // db4 wavedec, 4 levels
  float a1[14], d1[14];
  dwt_step<21>(xx, a1, d1);
#pragma unroll
  for (int i = 0; i < 14; i++) cb[(64 + i) << 10] = d1[i];
  float a2[10], d2[10];
  dwt_step<14>(a1, a2, d2);
#pragma unroll
  for (int i = 0; i < 10; i++) cb[(54 + i) << 10] = d2[i];
  float a3[8], d3[8];
  dwt_step<10>(a2, a3, d3);
#pragma unroll
  for (int i = 0; i < 8; i++) cb[(46 + i) << 10] = d3[i];
  float a4[7], d4[7];
  dwt_step<8>(a3, a4, d4);
#pragma unroll
  for (int i = 0; i < 7; i++) {
    cb[(32 + i) << 10] = a4[i];
    cb[(39 + i) << 10] = d4[i];
  }
}

// ---------------- kernel 0: transpose conv weights [64][78][3] -> [78][3][64] ----------------
__global__ __launch_bounds__(256) void transpose_w_kernel(const float* __restrict__ cw,
                                                          float* __restrict__ wT) {
  int idx = blockIdx.x * 256 + threadIdx.x;
  if (idx < 64 * 78 * 3) {
    int o = idx / 234;
    int r = idx - o * 234;
    int c = r / 3;
    int k = r - c * 3;
    wT[(c * 3 + k) * 64 + o] = cw[idx];
  }
}

// ---------------- kernel 2: conv(k=3,pad=1) + bias + relu + maxpool2 ----------------
// block: one b, 32 pooled positions, all 64 channels. thread: 4 s-pos x 4 ch.
__global__ __launch_bounds__(256) void conv_pool_kernel(const float* __restrict__ comb,
                                                        const float* __restrict__ wT,
                                                        const float* __restrict__ cbias,
                                                        float* __restrict__ y) {
  __shared__ __align__(16) float xs[39 * 68];
  __shared__ __align__(16) float wl[39 * 192];
  __shared__ float bl[64];

  const int tid = threadIdx.x;
  const int b = blockIdx.y;
  const int t0 = blockIdx.x * 32;
  const int s0 = 2 * t0;
  const int tc = tid & 15;   // position group: pooled t0+2tc, t0+2tc+1
  const int tr = tid >> 4;   // channel group: o = 4*tr .. 4*tr+3

  if (tid < 64) bl[tid] = cbias[tid];

  float acc[4][4];
#pragma unroll
  for (int i = 0; i < 4; i++)
#pragma unroll
    for (int n = 0; n < 4; n++) acc[i][n] = 0.f;

  for (int cs = 0; cs < 78; cs += 39) {
    __syncthreads();
    for (int idx = tid; idx < 39 * 66; idx += 256) {
      int c = idx / 66;
      int j = idx - c * 66;
      int s = s0 - 1 + j;
      xs[c * 68 + j] = (s >= 0 && s < 1024) ? comb[((b * 78 + cs + c) << 10) + s] : 0.f;
    }
    for (int idx = tid; idx < 39 * 192; idx += 256) wl[idx] = wT[cs * 192 + idx];
    __syncthreads();

    for (int c = 0; c < 39; c++) {
      const float* xrow = &xs[c * 68 + 4 * tc];   // 16B-aligned (68*4=272 ≡ 0 mod 16)
      float4 x4 = *(const float4*)xrow;
      float2 x2 = *(const float2*)(xrow + 4);
      float xv[6] = {x4.x, x4.y, x4.z, x4.w, x2.x, x2.y};
#pragma unroll
      for (int k = 0; k < 3; k++) {
        float4 w4 = ((const float4*)wl)[(c * 3 + k) * 16 + tr];
#pragma unroll
        for (int i = 0; i < 4; i++) {
          acc[i][0] = fmaf(xv[i + k], w4.x, acc[i][0]);
          acc[i][1] = fmaf(xv[i + k], w4.y, acc[i][1]);
          acc[i][2] = fmaf(xv[i + k], w4.z, acc[i][2]);
          acc[i][3] = fmaf(xv[i + k], w4.w, acc[i][3]);
        }
      }
    }
  }

  // bias + relu + pool pairs -> y[b][t][64]
  const int o0 = tr * 4;
  float4 v0, v1;
  float* pv0 = &v0.x;
  float* pv1 = &v1.x;
#pragma unroll
  for (int n = 0; n < 4; n++) {
    float bi = bl[o0 + n];
    pv0[n] = fmaxf(fmaxf(acc[0][n], acc[1][n]) + bi, 0.f);
    pv1[n] = fmaxf(fmaxf(acc[2][n], acc[3][n]) + bi, 0.f);
  }
  const int t = t0 + 2 * tc;
  ((float4*)y)[(b * 512 + t) * 16 + tr] = v0;
  ((float4*)y)[(b * 512 + t + 1) * 16 + tr] = v1;
}

// ---------------- kernel 3: X_proj = y @ w_ih^T + (b_ih + b_hh) ----------------
// rows R = b*512 + t (131072 rows of 64), out 128 gates per row.
__global__ __launch_bounds__(256) void proj_kernel(const float* __restrict__ y,
                                                   const float* __restrict__ w_ih,
                                                   const float* __restrict__ b_ih,
                                                   const float* __restrict__ b_hh,
                                                   float* __restrict__ Xp) {
  __shared__ __align__(16) float yl[32 * 68];
  __shared__ __align__(16) float wl[128 * 68];
  __shared__ float bl[128];

  const int tid = threadIdx.x;
  const int R0 = blockIdx.x * 32;

  for (int idx = tid; idx < 2048; idx += 256) {
    int r = idx >> 6, j = idx & 63;
    yl[r * 68 + j] = y[R0 * 64 + idx];
  }
  for (int idx = tid; idx < 8192; idx += 256) {
    int g = idx >> 6, j = idx & 63;
    wl[g * 68 + j] = w_ih[idx];
  }
  if (tid < 128) bl[tid] = b_ih[tid] + b_hh[tid];
  __syncthreads();

  const int rq = tid & 7, gq = tid >> 3;
  const int r0 = rq * 4, g0 = gq * 4;
  float acc[4][4];
#pragma unroll
  for (int i = 0; i < 4; i++)
#pragma unroll
    for (int n = 0; n < 4; n++) acc[i][n] = 0.f;

  for (int jq = 0; jq < 16; jq++) {
    const int j = jq * 4;
    float4 yv[4], wv[4];
#pragma unroll
    for (int i = 0; i < 4; i++) yv[i] = *(const float4*)&yl[(r0 + i) * 68 + j];
#pragma unroll
    for (int n = 0; n < 4; n++) wv[n] = *(const float4*)&wl[(g0 + n) * 68 + j];
#pragma unroll
    for (int i = 0; i < 4; i++)
#pragma unroll
      for (int n = 0; n < 4; n++) {
        acc[i][n] = fmaf(yv[i].x, wv[n].x, acc[i][n]);
        acc[i][n] = fmaf(yv[i].y, wv[n].y, acc[i][n]);
        acc[i][n] = fmaf(yv[i].z, wv[n].z, acc[i][n]);
        acc[i][n] = fmaf(yv[i].w, wv[n].w, acc[i][n]);
      }
  }

#pragma unroll
  for (int i = 0; i < 4; i++) {
    float4 o;
    o.x = acc[i][0] + bl[g0];
    o.y = acc[i][1] + bl[g0 + 1];
    o.z = acc[i][2] + bl[g0 + 2];
    o.w = acc[i][3] + bl[g0 + 3];
    *(float4*)&Xp[(R0 + r0 + i) * 128 + g0] = o;
  }
}

// ---------------- kernel 4: LSTM recurrence + fc ----------------
// R3 changes:
//  - __launch_bounds__(64, 1): allocator free to keep all weights in VGPRs
//    (R2/R3 showed VGPR_Count=48 < the 64 weight floats -> spill to AGPR/loop)
//  - 2 batches interleaved per wave: independent chains fill each other's
//    dependency stalls (transcendental + readlane latency); weights shared.
typedef float float2v __attribute__((ext_vector_type(2)));

__device__ __forceinline__ float bcast_lane(float v, int k) {
  return __uint_as_float(__builtin_amdgcn_readlane(__float_as_uint(v), k));
}

#if __has_builtin(__builtin_amdgcn_permlane32_swap)
// returns, for lanes 0..31, the value held by lane (j+32); VALU-only, no DS.
__device__ __forceinline__ float swap_half(float x) {
  auto r = __builtin_amdgcn_permlane32_swap(__float_as_uint(x), __float_as_uint(x),
                                            false, false);
  return __uint_as_float(r[1]);
}
#else
__device__ __forceinline__ float swap_half(float x) { return __shfl_down(x, 32); }
#endif

// one LSTM timestep for one batch element (all 64 lanes participate;
// lane L handles gates L and L+64; h,c valid on lanes 0..31)
__device__ __forceinline__ void lstm_step(float& h, float& c, float xA, float xB,
                                          const float2v* __restrict__ w2, bool lo) {
  float2v a2[4];
  a2[0] = (float2v){xA, xB};
  a2[1] = (float2v){0.f, 0.f};
  a2[2] = (float2v){0.f, 0.f};
  a2[3] = (float2v){0.f, 0.f};
#pragma unroll
  for (int k = 0; k < 32; k++) {
    float hk = bcast_lane(h, k);            // v_readlane_b32 (SGPR broadcast)
    float2v hk2 = (float2v){hk, hk};
    a2[k & 3] = __builtin_elementwise_fma(hk2, w2[k], a2[k & 3]);  // v_pk_fma_f32
  }
  float2v g2 = (a2[0] + a2[1]) + (a2[2] + a2[3]);
  float gA = g2.x, gB = g2.y;

  // sA = sigmoid(gA) on all lanes (i for lo, f for hi)
  float eA = __expf(-gA);
  float sA = __builtin_amdgcn_rcpf(1.0f + eA);

  // sB: tanh(gB) on lo lanes (g), sigmoid(gB) on hi lanes (o) — one exp+rcp
  float gBc = fmaxf(fminf(gB, 15.f), -15.f);
  float arg = lo ? (2.f * gBc) : (-gB);
  float eB = __expf(arg);
  float num = lo ? (eB - 1.f) : 1.f;
  float sB = num * __builtin_amdgcn_rcpf(eB + 1.f);

  float fv = swap_half(sA);                 // sig(f_j) -> lane j
  float ov = swap_half(sB);                 // sig(o_j) -> lane j
  c = fmaf(fv, c, sA * sB);                 // c = f*c + i*g   (valid lanes<32)
  float cc = fmaxf(fminf(c, 15.f), -15.f);
  float ec = __expf(2.f * cc);
  h = ov * (ec - 1.f) * __builtin_amdgcn_rcpf(ec + 1.f);  // h = o*tanh(c)
}

__global__ __launch_bounds__(64, 1) void lstm_fc_kernel(const float* __restrict__ Xp,
                                                        const float* __restrict__ w_hh,
                                                        const float* __restrict__ fc_w,
                                                        const float* __restrict__ fc_b,
                                                        float* __restrict__ out) {
  const int b0 = blockIdx.x * 2;
  const int L = threadIdx.x;
  const bool lo = (L < 32);

  // weights: rows L and L+64 of w_hh, packed as float2 per k (shared by both batches)
  const float4* rA = (const float4*)(w_hh + L * 32);
  const float4* rB = (const float4*)(w_hh + (L + 64) * 32);
  float2v w2[32];
#pragma unroll
  for (int q = 0; q < 8; q++) {
    float4 a4 = rA[q], b4 = rB[q];
    w2[4 * q + 0] = (float2v){a4.x, b4.x};
    w2[4 * q + 1] = (float2v){a4.y, b4.y};
    w2[4 * q + 2] = (float2v){a4.z, b4.z};
    w2[4 * q + 3] = (float2v){a4.w, b4.w};
  }

  const float* xp0 = Xp + (size_t)b0 * 512 * 128;
  const float* xp1 = xp0 + 512 * 128;
  float h0 = 0.f, c0 = 0.f, h1 = 0.f, c1 = 0.f;

  // 4-deep prefetch registers per batch
  float pA0[4], pB0[4], pA1[4], pB1[4];
#pragma unroll
  for (int u = 0; u < 4; u++) {
    pA0[u] = xp0[u * 128 + L];
    pB0[u] = xp0[u * 128 + 64 + L];
    pA1[u] = xp1[u * 128 + L];
    pB1[u] = xp1[u * 128 + 64 + L];
  }

  for (int t0 = 0; t0 < 512; t0 += 4) {
    float cA0[4], cB0[4], cA1[4], cB1[4];
#pragma unroll
    for (int u = 0; u < 4; u++) {
      cA0[u] = pA0[u]; cB0[u] = pB0[u];
      cA1[u] = pA1[u]; cB1[u] = pB1[u];
    }
    if (t0 + 4 < 512) {
#pragma unroll
      for (int u = 0; u < 4; u++) {
        pA0[u] = xp0[(t0 + 4 + u) * 128 + L];
        pB0[u] = xp0[(t0 + 4 + u) * 128 + 64 + L];
        pA1[u] = xp1[(t0 + 4 + u) * 128 + L];
        pB1[u] = xp1[(t0 + 4 + u) * 128 + 64 + L];
      }
    }
#pragma unroll
    for (int u = 0; u < 4; u++) {
      lstm_step(h0, c0, cA0[u], cB0[u], w2, lo);
      lstm_step(h1, c1, cA1[u], cB1[u], w2, lo);
    }
  }

  float fw = fc_w[L & 31];
  float v0 = lo ? h0 * fw : 0.f;
  float v1 = lo ? h1 * fw : 0.f;
#pragma unroll
  for (int off = 32; off > 0; off >>= 1) {
    v0 += __shfl_down(v0, off);
    v1 += __shfl_down(v1, off);
  }
  if (L == 0) {
    float fb = fc_b[0];
    out[b0] = v0 + fb;
    out[b0 + 1] = v1 + fb;
  }
}

// ---------------- launch ----------------
extern "C" void kernel_launch(void* const* d_in, const int* in_sizes, int n_in,
                              void* d_out, int out_size, void* d_ws, size_t ws_size,
                              hipStream_t stream) {
  const float* x      = (const float*)d_in[0];  // [256,1024,21]
  const float* conv_w = (const float*)d_in[1];  // [64,78,3]
  const float* conv_b = (const float*)d_in[2];  // [64]
  const float* w_ih   = (const float*)d_in[3];  // [128,64]
  const float* w_hh   = (const float*)d_in[4];  // [128,32]
  const float* b_ih   = (const float*)d_in[5];  // [128]
  const float* b_hh   = (const float*)d_in[6];  // [128]
  const float* fc_w   = (const float*)d_in[7];  // [1,32]
  const float* fc_b   = (const float*)d_in[8];  // [1]
  float* out = (float*)d_out;                   // [256,1]

  char* wsb = (char*)d_ws;
  float* comb = (float*)wsb;                          // 256*78*1024*4 = 81,788,928 B
  float* Xp   = (float*)wsb;                          // aliases comb (dead after conv)
  float* y    = (float*)(wsb + 81788928);             // 256*512*64*4 = 33,554,432 B
  float* wT   = (float*)(wsb + 81788928 + 33554432);  // 78*3*64*4 = 59,904 B

  transpose_w_kernel<<<dim3(59), dim3(256), 0, stream>>>(conv_w, wT);
  features_kernel<<<dim3(1024), dim3(256), 0, stream>>>(x, comb);
  conv_pool_kernel<<<dim3(16, 256), dim3(256), 0, stream>>>(comb, wT, conv_b, y);
  proj_kernel<<<dim3(4096), dim3(256), 0, stream>>>(y, w_ih, b_ih, b_hh, Xp);
  lstm_fc_kernel<<<dim3(128), dim3(64), 0, stream>>>(Xp, w_hh, fc_w, fc_b, out);
}

// Round 5
// 402.656 us; speedup vs baseline: 1.3931x; 1.3931x over previous
//
#include <hip/hip_runtime.h>
#include <math.h>

// ---------------- constants ----------------
constexpr float DLO[8] = {-0.010597401784997278f, 0.032883011666982945f, 0.030841381835986965f,
                          -0.18703481171888114f, -0.02798376941698385f, 0.6308807679295904f,
                          0.7148465705525415f, 0.23037781330885523f};
constexpr float DHI[8] = {-0.23037781330885523f, 0.7148465705525415f, -0.6308807679295904f,
                          -0.02798376941698385f, 0.18703481171888114f, 0.030841381835986965f,
                          -0.032883011666982945f, -0.010597401784997278f};

// cos/sin(2*pi*m/21), m=0..20 — compile-time tables (replaces libm sincosf)
constexpr float CT21[21] = {
  1.0f,          0.95557281f,  0.82623877f,  0.62348980f,  0.36534102f,  0.07473009f,
  -0.22252093f, -0.5f,        -0.73305187f, -0.90096887f, -0.98883083f,
  -0.98883083f, -0.90096887f, -0.73305187f, -0.5f,        -0.22252093f,
  0.07473009f,   0.36534102f,  0.62348980f,  0.82623877f,  0.95557281f};
constexpr float ST21[21] = {
  0.0f,          0.29475517f,  0.56332006f,  0.78183148f,  0.93087375f,  0.99720380f,
  0.97492791f,   0.86602540f,  0.68017274f,  0.43388374f,  0.14904227f,
  -0.14904227f, -0.43388374f, -0.68017274f, -0.86602540f, -0.97492791f,
  -0.99720380f, -0.93087375f, -0.78183148f, -0.56332006f, -0.29475517f};

// dwt, mode='symmetric' with pywt phase: left pad 6, right pad 7
// out[i] = sum_j xe[2i+j] * filt[7-j]
template<int N>
__device__ __forceinline__ void dwt_step(const float* in, float* a, float* d) {
  constexpr int NO = (N + 7) / 2;
#pragma unroll
  for (int i = 0; i < NO; i++) {
    float sa = 0.f, sd = 0.f;
#pragma unroll
    for (int j = 0; j < 8; j++) {
      int rel = 2 * i + j - 6;
      int idx = (rel < 0) ? (-rel - 1) : ((rel >= N) ? (2 * N - rel - 1) : rel);
      float v = in[idx];
      sa = fmaf(v, DLO[7 - j], sa);
      sd = fmaf(v, DHI[7 - j], sd);
    }
    a[i] = sa;
    d[i] = sd;
  }
}

// ---------------- kernel 1: features ----------------
// combined[b][row][s], rows: 0..20 x, 21..31 |rfft|, 32..38 cA4, 39..45 cD4,
// 46..53 cD3, 54..63 cD2, 64..77 cD1
__global__ __launch_bounds__(256) void features_kernel(const float* __restrict__ x,
                                                       float* __restrict__ comb) {
  __shared__ float xl[256 * 21];
  const int tid = threadIdx.x;
  const int g0 = blockIdx.x * 256;
  for (int idx = tid; idx < 256 * 21; idx += 256) xl[idx] = x[g0 * 21 + idx];
  __syncthreads();

  const int gid = g0 + tid;
  const int b = gid >> 10, s = gid & 1023;

  float xx[21];
#pragma unroll
  for (int t = 0; t < 21; t++) xx[t] = xl[tid * 21 + t];

  float* cb = comb + ((b * 78) << 10) + s;

  // raw copy
#pragma unroll
  for (int t = 0; t < 21; t++) cb[t << 10] = xx[t];

  // 21-point DFT magnitudes (k = 0..10), trig from constexpr tables
#pragma unroll
  for (int k = 0; k < 11; k++) {
    float re = 0.f, im = 0.f;
#pragma unroll
    for (int t = 0; t < 21; t++) {
      constexpr int M = 21;
      const int m = (k * t) % M;  // compile-time under unroll
      re = fmaf(xx[t], CT21[m], re);
      im = fmaf(xx[t], ST21[m], im);
    }
    cb[(21 + k) << 10] = sqrtf(re * re + im * im);
  }

  // db4 wavedec, 4 levels
  float a1[14], d1[14];
  dwt_step<21>(xx, a1, d1);
#pragma unroll
  for (int i = 0; i < 14; i++) cb[(64 + i) << 10] = d1[i];
  float a2[10], d2[10];
  dwt_step<14>(a1, a2, d2);
#pragma unroll
  for (int i = 0; i < 10; i++) cb[(54 + i) << 10] = d2[i];
  float a3[8], d3[8];
  dwt_step<10>(a2, a3, d3);
#pragma unroll
  for (int i = 0; i < 8; i++) cb[(46 + i) << 10] = d3[i];
  float a4[7], d4[7];
  dwt_step<8>(a3, a4, d4);
#pragma unroll
  for (int i = 0; i < 7; i++) {
    cb[(32 + i) << 10] = a4[i];
    cb[(39 + i) << 10] = d4[i];
  }
}

// ---------------- kernel 0: transpose conv weights [64][78][3] -> [78][3][64] ----------------
__global__ __launch_bounds__(256) void transpose_w_kernel(const float* __restrict__ cw,
                                                          float* __restrict__ wT) {
  int idx = blockIdx.x * 256 + threadIdx.x;
  if (idx < 64 * 78 * 3) {
    int o = idx / 234;
    int r = idx - o * 234;
    int c = r / 3;
    int k = r - c * 3;
    wT[(c * 3 + k) * 64 + o] = cw[idx];
  }
}

// ---------------- kernel 2: conv(k=3,pad=1) + bias + relu + maxpool2 ----------------
// block: one b, 32 pooled positions, all 64 channels. thread: 4 s-pos x 4 ch.
__global__ __launch_bounds__(256) void conv_pool_kernel(const float* __restrict__ comb,
                                                        const float* __restrict__ wT,
                                                        const float* __restrict__ cbias,
                                                        float* __restrict__ y) {
  __shared__ __align__(16) float xs[39 * 68];
  __shared__ __align__(16) float wl[39 * 192];
  __shared__ float bl[64];

  const int tid = threadIdx.x;
  const int b = blockIdx.y;
  const int t0 = blockIdx.x * 32;
  const int s0 = 2 * t0;
  const int tc = tid & 15;   // position group: pooled t0+2tc, t0+2tc+1
  const int tr = tid >> 4;   // channel group: o = 4*tr .. 4*tr+3

  if (tid < 64) bl[tid] = cbias[tid];

  float acc[4][4];
#pragma unroll
  for (int i = 0; i < 4; i++)
#pragma unroll
    for (int n = 0; n < 4; n++) acc[i][n] = 0.f;

  for (int cs = 0; cs < 78; cs += 39) {
    __syncthreads();
    for (int idx = tid; idx < 39 * 66; idx += 256) {
      int c = idx / 66;
      int j = idx - c * 66;
      int s = s0 - 1 + j;
      xs[c * 68 + j] = (s >= 0 && s < 1024) ? comb[((b * 78 + cs + c) << 10) + s] : 0.f;
    }
    for (int idx = tid; idx < 39 * 192; idx += 256) wl[idx] = wT[cs * 192 + idx];
    __syncthreads();

    for (int c = 0; c < 39; c++) {
      const float* xrow = &xs[c * 68 + 4 * tc];   // 16B-aligned (68*4=272 ≡ 0 mod 16)
      float4 x4 = *(const float4*)xrow;
      float2 x2 = *(const float2*)(xrow + 4);
      float xv[6] = {x4.x, x4.y, x4.z, x4.w, x2.x, x2.y};
#pragma unroll
      for (int k = 0; k < 3; k++) {
        float4 w4 = ((const float4*)wl)[(c * 3 + k) * 16 + tr];
#pragma unroll
        for (int i = 0; i < 4; i++) {
          acc[i][0] = fmaf(xv[i + k], w4.x, acc[i][0]);
          acc[i][1] = fmaf(xv[i + k], w4.y, acc[i][1]);
          acc[i][2] = fmaf(xv[i + k], w4.z, acc[i][2]);
          acc[i][3] = fmaf(xv[i + k], w4.w, acc[i][3]);
        }
      }
    }
  }

  // bias + relu + pool pairs -> y[b][t][64]
  const int o0 = tr * 4;
  float4 v0, v1;
  float* pv0 = &v0.x;
  float* pv1 = &v1.x;
#pragma unroll
  for (int n = 0; n < 4; n++) {
    float bi = bl[o0 + n];
    pv0[n] = fmaxf(fmaxf(acc[0][n], acc[1][n]) + bi, 0.f);
    pv1[n] = fmaxf(fmaxf(acc[2][n], acc[3][n]) + bi, 0.f);
  }
  const int t = t0 + 2 * tc;
  ((float4*)y)[(b * 512 + t) * 16 + tr] = v0;
  ((float4*)y)[(b * 512 + t + 1) * 16 + tr] = v1;
}

// ---------------- kernel 3: X_proj = y @ w_ih^T + (b_ih + b_hh) ----------------
// rows R = b*512 + t (131072 rows of 64), out 128 gates per row.
__global__ __launch_bounds__(256) void proj_kernel(const float* __restrict__ y,
                                                   const float* __restrict__ w_ih,
                                                   const float* __restrict__ b_ih,
                                                   const float* __restrict__ b_hh,
                                                   float* __restrict__ Xp) {
  __shared__ __align__(16) float yl[32 * 68];
  __shared__ __align__(16) float wl[128 * 68];
  __shared__ float bl[128];

  const int tid = threadIdx.x;
  const int R0 = blockIdx.x * 32;

  for (int idx = tid; idx < 2048; idx += 256) {
    int r = idx >> 6, j = idx & 63;
    yl[r * 68 + j] = y[R0 * 64 + idx];
  }
  for (int idx = tid; idx < 8192; idx += 256) {
    int g = idx >> 6, j = idx & 63;
    wl[g * 68 + j] = w_ih[idx];
  }
  if (tid < 128) bl[tid] = b_ih[tid] + b_hh[tid];
  __syncthreads();

  const int rq = tid & 7, gq = tid >> 3;
  const int r0 = rq * 4, g0 = gq * 4;
  float acc[4][4];
#pragma unroll
  for (int i = 0; i < 4; i++)
#pragma unroll
    for (int n = 0; n < 4; n++) acc[i][n] = 0.f;

  for (int jq = 0; jq < 16; jq++) {
    const int j = jq * 4;
    float4 yv[4], wv[4];
#pragma unroll
    for (int i = 0; i < 4; i++) yv[i] = *(const float4*)&yl[(r0 + i) * 68 + j];
#pragma unroll
    for (int n = 0; n < 4; n++) wv[n] = *(const float4*)&wl[(g0 + n) * 68 + j];
#pragma unroll
    for (int i = 0; i < 4; i++)
#pragma unroll
      for (int n = 0; n < 4; n++) {
        acc[i][n] = fmaf(yv[i].x, wv[n].x, acc[i][n]);
        acc[i][n] = fmaf(yv[i].y, wv[n].y, acc[i][n]);
        acc[i][n] = fmaf(yv[i].z, wv[n].z, acc[i][n]);
        acc[i][n] = fmaf(yv[i].w, wv[n].w, acc[i][n]);
      }
  }

#pragma unroll
  for (int i = 0; i < 4; i++) {
    float4 o;
    o.x = acc[i][0] + bl[g0];
    o.y = acc[i][1] + bl[g0 + 1];
    o.z = acc[i][2] + bl[g0 + 2];
    o.w = acc[i][3] + bl[g0 + 3];
    *(float4*)&Xp[(R0 + r0 + i) * 128 + g0] = o;
  }
}

// ---------------- kernel 4: LSTM recurrence + fc ----------------
// R5 changes (de-spill; R4 showed issue-bound with AGPR-spill moves):
//  - amdgpu_waves_per_eu(1,1): pin allocator occupancy target to 1 wave/EU
//    (512-VGPR budget) — __launch_bounds__ min-waves alone didn't move it
//  - scalar v_fma_f32 (VOP3) instead of v_pk_fma_f32 (VOP3P): VOP3 can read
//    AGPR operands directly on gfx950, so residual AGPR placement costs 0 moves
//  - back to 1 batch/wave (grid 256): kernel is issue-bound, fewer instrs wins
__device__ __forceinline__ float bcast_lane(float v, int k) {
  return __uint_as_float(__builtin_amdgcn_readlane(__float_as_uint(v), k));
}

#if __has_builtin(__builtin_amdgcn_permlane32_swap)
// returns, for lanes 0..31, the value held by lane (j+32); VALU-only, no DS.
__device__ __forceinline__ float swap_half(float x) {
  auto r = __builtin_amdgcn_permlane32_swap(__float_as_uint(x), __float_as_uint(x),
                                            false, false);
  return __uint_as_float(r[1]);
}
#else
__device__ __forceinline__ float swap_half(float x) { return __shfl_down(x, 32); }
#endif

// one LSTM timestep (lane L handles gates L and L+64; h,c valid on lanes 0..31)
__device__ __forceinline__ void lstm_step(float& h, float& c, float xA, float xB,
                                          const float* wA, const float* wB, bool lo) {
  float aA0 = xA, aA1 = 0.f, aB0 = xB, aB1 = 0.f;
#pragma unroll
  for (int k = 0; k < 32; k += 2) {
    float hk0 = bcast_lane(h, k);
    float hk1 = bcast_lane(h, k + 1);
    aA0 = fmaf(hk0, wA[k], aA0);
    aB0 = fmaf(hk0, wB[k], aB0);
    aA1 = fmaf(hk1, wA[k + 1], aA1);
    aB1 = fmaf(hk1, wB[k + 1], aB1);
  }
  float gA = aA0 + aA1;
  float gB = aB0 + aB1;

  // sA = sigmoid(gA) on all lanes (i for lo, f for hi)
  float eA = __expf(-gA);
  float sA = __builtin_amdgcn_rcpf(1.0f + eA);

  // sB: tanh(gB) on lo lanes (g), sigmoid(gB) on hi lanes (o) — one exp+rcp
  float gBc = fmaxf(fminf(gB, 15.f), -15.f);
  float arg = lo ? (2.f * gBc) : (-gB);
  float eB = __expf(arg);
  float num = lo ? (eB - 1.f) : 1.f;
  float sB = num * __builtin_amdgcn_rcpf(eB + 1.f);

  float fv = swap_half(sA);                 // sig(f_j) -> lane j
  float ov = swap_half(sB);                 // sig(o_j) -> lane j
  c = fmaf(fv, c, sA * sB);                 // c = f*c + i*g   (valid lanes<32)
  float cc = fmaxf(fminf(c, 15.f), -15.f);
  float ec = __expf(2.f * cc);
  h = ov * (ec - 1.f) * __builtin_amdgcn_rcpf(ec + 1.f);  // h = o*tanh(c)
}

__global__ __launch_bounds__(64, 1)
__attribute__((amdgpu_waves_per_eu(1, 1)))
void lstm_fc_kernel(const float* __restrict__ Xp,
                    const float* __restrict__ w_hh,
                    const float* __restrict__ fc_w,
                    const float* __restrict__ fc_b,
                    float* __restrict__ out) {
  const int b = blockIdx.x;
  const int L = threadIdx.x;
  const bool lo = (L < 32);

  // weights: rows L and L+64 of w_hh (64 floats/lane, VGPR-resident)
  float wA[32], wB[32];
  {
    const float4* rA = (const float4*)(w_hh + L * 32);
    const float4* rB = (const float4*)(w_hh + (L + 64) * 32);
#pragma unroll
    for (int q = 0; q < 8; q++) {
      float4 a4 = rA[q], b4 = rB[q];
      wA[4 * q + 0] = a4.x; wA[4 * q + 1] = a4.y; wA[4 * q + 2] = a4.z; wA[4 * q + 3] = a4.w;
      wB[4 * q + 0] = b4.x; wB[4 * q + 1] = b4.y; wB[4 * q + 2] = b4.z; wB[4 * q + 3] = b4.w;
    }
  }

  const float* xp = Xp + (size_t)b * 512 * 128;
  float h = 0.f, c = 0.f;

  // 4-deep prefetch registers
  float pA[4], pB[4];
#pragma unroll
  for (int u = 0; u < 4; u++) {
    pA[u] = xp[u * 128 + L];
    pB[u] = xp[u * 128 + 64 + L];
  }

  for (int t0 = 0; t0 < 512; t0 += 4) {
    float cA[4], cB[4];
#pragma unroll
    for (int u = 0; u < 4; u++) { cA[u] = pA[u]; cB[u] = pB[u]; }
    if (t0 + 4 < 512) {
#pragma unroll
      for (int u = 0; u < 4; u++) {
        pA[u] = xp[(t0 + 4 + u) * 128 + L];
        pB[u] = xp[(t0 + 4 + u) * 128 + 64 + L];
      }
    }
#pragma unroll
    for (int u = 0; u < 4; u++) {
      lstm_step(h, c, cA[u], cB[u], wA, wB, lo);
    }
  }

  float v = lo ? h * fc_w[L & 31] : 0.f;
#pragma unroll
  for (int off = 32; off > 0; off >>= 1) v += __shfl_down(v, off);
  if (L == 0) out[b] = v + fc_b[0];
}

// ---------------- launch ----------------
extern "C" void kernel_launch(void* const* d_in, const int* in_sizes, int n_in,
                              void* d_out, int out_size, void* d_ws, size_t ws_size,
                              hipStream_t stream) {
  const float* x      = (const float*)d_in[0];  // [256,1024,21]
  const float* conv_w = (const float*)d_in[1];  // [64,78,3]
  const float* conv_b = (const float*)d_in[2];  // [64]
  const float* w_ih   = (const float*)d_in[3];  // [128,64]
  const float* w_hh   = (const float*)d_in[4];  // [128,32]
  const float* b_ih   = (const float*)d_in[5];  // [128]
  const float* b_hh   = (const float*)d_in[6];  // [128]
  const float* fc_w   = (const float*)d_in[7];  // [1,32]
  const float* fc_b   = (const float*)d_in[8];  // [1]
  float* out = (float*)d_out;                   // [256,1]

  char* wsb = (char*)d_ws;
  float* comb = (float*)wsb;                          // 256*78*1024*4 = 81,788,928 B
  float* Xp   = (float*)wsb;                          // aliases comb (dead after conv)
  float* y    = (float*)(wsb + 81788928);             // 256*512*64*4 = 33,554,432 B
  float* wT   = (float*)(wsb + 81788928 + 33554432);  // 78*3*64*4 = 59,904 B

  transpose_w_kernel<<<dim3(59), dim3(256), 0, stream>>>(conv_w, wT);
  features_kernel<<<dim3(1024), dim3(256), 0, stream>>>(x, comb);
  conv_pool_kernel<<<dim3(16, 256), dim3(256), 0, stream>>>(comb, wT, conv_b, y);
  proj_kernel<<<dim3(4096), dim3(256), 0, stream>>>(y, w_ih, b_ih, b_hh, Xp);
  lstm_fc_kernel<<<dim3(256), dim3(64), 0, stream>>>(Xp, w_hh, fc_w, fc_b, out);
}

// Round 6
// 398.761 us; speedup vs baseline: 1.4067x; 1.0098x over previous
//
#include <hip/hip_runtime.h>
#include <math.h>

// ---------------- constants ----------------
constexpr float DLO[8] = {-0.010597401784997278f, 0.032883011666982945f, 0.030841381835986965f,
                          -0.18703481171888114f, -0.02798376941698385f, 0.6308807679295904f,
                          0.7148465705525415f, 0.23037781330885523f};
constexpr float DHI[8] = {-0.23037781330885523f, 0.7148465705525415f, -0.6308807679295904f,
                          -0.02798376941698385f, 0.18703481171888114f, 0.030841381835986965f,
                          -0.032883011666982945f, -0.010597401784997278f};

// cos/sin(2*pi*m/21), m=0..20 — compile-time tables (replaces libm sincosf)
constexpr float CT21[21] = {
  1.0f,          0.95557281f,  0.82623877f,  0.62348980f,  0.36534102f,  0.07473009f,
  -0.22252093f, -0.5f,        -0.73305187f, -0.90096887f, -0.98883083f,
  -0.98883083f, -0.90096887f, -0.73305187f, -0.5f,        -0.22252093f,
  0.07473009f,   0.36534102f,  0.62348980f,  0.82623877f,  0.95557281f};
constexpr float ST21[21] = {
  0.0f,          0.29475517f,  0.56332006f,  0.78183148f,  0.93087375f,  0.99720380f,
  0.97492791f,   0.86602540f,  0.68017274f,  0.43388374f,  0.14904227f,
  -0.14904227f, -0.43388374f, -0.68017274f, -0.86602540f, -0.97492791f,
  -0.99720380f, -0.93087375f, -0.78183148f, -0.56332006f, -0.29475517f};

// dwt, mode='symmetric' with pywt phase: left pad 6, right pad 7
// out[i] = sum_j xe[2i+j] * filt[7-j]
template<int N>
__device__ __forceinline__ void dwt_step(const float* in, float* a, float* d) {
  constexpr int NO = (N + 7) / 2;
#pragma unroll
  for (int i = 0; i < NO; i++) {
    float sa = 0.f, sd = 0.f;
#pragma unroll
    for (int j = 0; j < 8; j++) {
      int rel = 2 * i + j - 6;
      int idx = (rel < 0) ? (-rel - 1) : ((rel >= N) ? (2 * N - rel - 1) : rel);
      float v = in[idx];
      sa = fmaf(v, DLO[7 - j], sa);
      sd = fmaf(v, DHI[7 - j], sd);
    }
    a[i] = sa;
    d[i] = sd;
  }
}

// ---------------- kernel 1: features ----------------
__global__ __launch_bounds__(256) void features_kernel(const float* __restrict__ x,
                                                       float* __restrict__ comb) {
  __shared__ float xl[256 * 21];
  const int tid = threadIdx.x;
  const int g0 = blockIdx.x * 256;
  for (int idx = tid; idx < 256 * 21; idx += 256) xl[idx] = x[g0 * 21 + idx];
  __syncthreads();

  const int gid = g0 + tid;
  const int b = gid >> 10, s = gid & 1023;

  float xx[21];
#pragma unroll
  for (int t = 0; t < 21; t++) xx[t] = xl[tid * 21 + t];

  float* cb = comb + ((b * 78) << 10) + s;

  // raw copy
#pragma unroll
  for (int t = 0; t < 21; t++) cb[t << 10] = xx[t];

  // 21-point DFT magnitudes (k = 0..10), trig from constexpr tables
#pragma unroll
  for (int k = 0; k < 11; k++) {
    float re = 0.f, im = 0.f;
#pragma unroll
    for (int t = 0; t < 21; t++) {
      const int m = (k * t) % 21;  // compile-time under unroll
      re = fmaf(xx[t], CT21[m], re);
      im = fmaf(xx[t], ST21[m], im);
    }
    cb[(21 + k) << 10] = sqrtf(re * re + im * im);
  }

  // db4 wavedec, 4 levels
  float a1[14], d1[14];
  dwt_step<21>(xx, a1, d1);
#pragma unroll
  for (int i = 0; i < 14; i++) cb[(64 + i) << 10] = d1[i];
  float a2[10], d2[10];
  dwt_step<14>(a1, a2, d2);
#pragma unroll
  for (int i = 0; i < 10; i++) cb[(54 + i) << 10] = d2[i];
  float a3[8], d3[8];
  dwt_step<10>(a2, a3, d3);
#pragma unroll
  for (int i = 0; i < 8; i++) cb[(46 + i) << 10] = d3[i];
  float a4[7], d4[7];
  dwt_step<8>(a3, a4, d4);
#pragma unroll
  for (int i = 0; i < 7; i++) {
    cb[(32 + i) << 10] = a4[i];
    cb[(39 + i) << 10] = d4[i];
  }
}

// ---------------- kernel 0: transpose conv weights [64][78][3] -> [78][3][64] ----------------
__global__ __launch_bounds__(256) void transpose_w_kernel(const float* __restrict__ cw,
                                                          float* __restrict__ wT) {
  int idx = blockIdx.x * 256 + threadIdx.x;
  if (idx < 64 * 78 * 3) {
    int o = idx / 234;
    int r = idx - o * 234;
    int c = r / 3;
    int k = r - c * 3;
    wT[(c * 3 + k) * 64 + o] = cw[idx];
  }
}

// ---------------- kernel 2: conv(k=3,pad=1) + bias + relu + maxpool2 ----------------
__global__ __launch_bounds__(256) void conv_pool_kernel(const float* __restrict__ comb,
                                                        const float* __restrict__ wT,
                                                        const float* __restrict__ cbias,
                                                        float* __restrict__ y) {
  __shared__ __align__(16) float xs[39 * 68];
  __shared__ __align__(16) float wl[39 * 192];
  __shared__ float bl[64];

  const int tid = threadIdx.x;
  const int b = blockIdx.y;
  const int t0 = blockIdx.x * 32;
  const int s0 = 2 * t0;
  const int tc = tid & 15;   // position group: pooled t0+2tc, t0+2tc+1
  const int tr = tid >> 4;   // channel group: o = 4*tr .. 4*tr+3

  if (tid < 64) bl[tid] = cbias[tid];

  float acc[4][4];
#pragma unroll
  for (int i = 0; i < 4; i++)
#pragma unroll
    for (int n = 0; n < 4; n++) acc[i][n] = 0.f;

  for (int cs = 0; cs < 78; cs += 39) {
    __syncthreads();
    for (int idx = tid; idx < 39 * 66; idx += 256) {
      int c = idx / 66;
      int j = idx - c * 66;
      int s = s0 - 1 + j;
      xs[c * 68 + j] = (s >= 0 && s < 1024) ? comb[((b * 78 + cs + c) << 10) + s] : 0.f;
    }
    for (int idx = tid; idx < 39 * 192; idx += 256) wl[idx] = wT[cs * 192 + idx];
    __syncthreads();

    for (int c = 0; c < 39; c++) {
      const float* xrow = &xs[c * 68 + 4 * tc];   // 16B-aligned
      float4 x4 = *(const float4*)xrow;
      float2 x2 = *(const float2*)(xrow + 4);
      float xv[6] = {x4.x, x4.y, x4.z, x4.w, x2.x, x2.y};
#pragma unroll
      for (int k = 0; k < 3; k++) {
        float4 w4 = ((const float4*)wl)[(c * 3 + k) * 16 + tr];
#pragma unroll
        for (int i = 0; i < 4; i++) {
          acc[i][0] = fmaf(xv[i + k], w4.x, acc[i][0]);
          acc[i][1] = fmaf(xv[i + k], w4.y, acc[i][1]);
          acc[i][2] = fmaf(xv[i + k], w4.z, acc[i][2]);
          acc[i][3] = fmaf(xv[i + k], w4.w, acc[i][3]);
        }
      }
    }
  }

  // bias + relu + pool pairs -> y[b][t][64]
  const int o0 = tr * 4;
  float4 v0, v1;
  float* pv0 = &v0.x;
  float* pv1 = &v1.x;
#pragma unroll
  for (int n = 0; n < 4; n++) {
    float bi = bl[o0 + n];
    pv0[n] = fmaxf(fmaxf(acc[0][n], acc[1][n]) + bi, 0.f);
    pv1[n] = fmaxf(fmaxf(acc[2][n], acc[3][n]) + bi, 0.f);
  }
  const int t = t0 + 2 * tc;
  ((float4*)y)[(b * 512 + t) * 16 + tr] = v0;
  ((float4*)y)[(b * 512 + t + 1) * 16 + tr] = v1;
}

// ---------------- kernel 3: X_proj = y @ w_ih^T + (b_ih + b_hh) ----------------
// R6: stores INTERLEAVED gate layout: position p(g) = 2*(g&63) + (g>>6), so the
// LSTM lane L reads one aligned float2 = (gate L, gate L+64) per step.
__global__ __launch_bounds__(256) void proj_kernel(const float* __restrict__ y,
                                                   const float* __restrict__ w_ih,
                                                   const float* __restrict__ b_ih,
                                                   const float* __restrict__ b_hh,
                                                   float* __restrict__ Xp) {
  __shared__ __align__(16) float yl[32 * 68];
  __shared__ __align__(16) float wl[128 * 68];
  __shared__ float bl[128];

  const int tid = threadIdx.x;
  const int R0 = blockIdx.x * 32;

  for (int idx = tid; idx < 2048; idx += 256) {
    int r = idx >> 6, j = idx & 63;
    yl[r * 68 + j] = y[R0 * 64 + idx];
  }
  for (int idx = tid; idx < 8192; idx += 256) {
    int g = idx >> 6, j = idx & 63;
    wl[g * 68 + j] = w_ih[idx];
  }
  if (tid < 128) bl[tid] = b_ih[tid] + b_hh[tid];
  __syncthreads();

  const int rq = tid & 7, gq = tid >> 3;
  const int r0 = rq * 4, g0 = gq * 4;
  float acc[4][4];
#pragma unroll
  for (int i = 0; i < 4; i++)
#pragma unroll
    for (int n = 0; n < 4; n++) acc[i][n] = 0.f;

  for (int jq = 0; jq < 16; jq++) {
    const int j = jq * 4;
    float4 yv[4], wv[4];
#pragma unroll
    for (int i = 0; i < 4; i++) yv[i] = *(const float4*)&yl[(r0 + i) * 68 + j];
#pragma unroll
    for (int n = 0; n < 4; n++) wv[n] = *(const float4*)&wl[(g0 + n) * 68 + j];
#pragma unroll
    for (int i = 0; i < 4; i++)
#pragma unroll
      for (int n = 0; n < 4; n++) {
        acc[i][n] = fmaf(yv[i].x, wv[n].x, acc[i][n]);
        acc[i][n] = fmaf(yv[i].y, wv[n].y, acc[i][n]);
        acc[i][n] = fmaf(yv[i].z, wv[n].z, acc[i][n]);
        acc[i][n] = fmaf(yv[i].w, wv[n].w, acc[i][n]);
      }
  }

#pragma unroll
  for (int i = 0; i < 4; i++) {
#pragma unroll
    for (int n = 0; n < 4; n++) {
      const int g = g0 + n;
      const int p = ((g & 63) << 1) | (g >> 6);  // interleaved position
      Xp[(R0 + r0 + i) * 128 + p] = acc[i][n] + bl[g];
    }
  }
}

// ---------------- kernel 4: LSTM recurrence + fc ----------------
// R6 changes:
//  - retry v_pk_fma_f32 now that amdgpu_waves_per_eu(1,1) is in place
//    (watch: if VGPR alloc still forces AGPR weights -> accvgpr moves -> revert)
//  - all 32 readlanes batched BEFORE the FMA block (pipeline SGPR writes)
//  - Xp interleaved: one float2 load per step per lane (was 2 scalar loads)
typedef float float2v __attribute__((ext_vector_type(2)));

__device__ __forceinline__ float bcast_lane(float v, int k) {
  return __uint_as_float(__builtin_amdgcn_readlane(__float_as_uint(v), k));
}

#if __has_builtin(__builtin_amdgcn_permlane32_swap)
// returns, for lanes 0..31, the value held by lane (j+32); VALU-only, no DS.
__device__ __forceinline__ float swap_half(float x) {
  auto r = __builtin_amdgcn_permlane32_swap(__float_as_uint(x), __float_as_uint(x),
                                            false, false);
  return __uint_as_float(r[1]);
}
#else
__device__ __forceinline__ float swap_half(float x) { return __shfl_down(x, 32); }
#endif

// one LSTM timestep (lane L handles gates L and L+64; h,c valid on lanes 0..31)
__device__ __forceinline__ void lstm_step(float& h, float& c, float2v xg,
                                          const float2v* __restrict__ w2, bool lo) {
  // phase 1: batched h-broadcast (32 independent v_readlane -> SGPRs)
  float hs[32];
#pragma unroll
  for (int k = 0; k < 32; k++) hs[k] = bcast_lane(h, k);

  // phase 2: packed gate matvec, 2 dep chains
  float2v a0 = xg, a1 = (float2v){0.f, 0.f};
#pragma unroll
  for (int k = 0; k < 32; k += 2) {
    float2v h0 = (float2v){hs[k], hs[k]};
    float2v h1 = (float2v){hs[k + 1], hs[k + 1]};
    a0 = __builtin_elementwise_fma(h0, w2[k], a0);
    a1 = __builtin_elementwise_fma(h1, w2[k + 1], a1);
  }
  float2v g2 = a0 + a1;
  float gA = g2.x, gB = g2.y;

  // sA = sigmoid(gA) on all lanes (i for lo, f for hi)
  float eA = __expf(-gA);
  float sA = __builtin_amdgcn_rcpf(1.0f + eA);

  // sB: tanh(gB) on lo lanes (g), sigmoid(gB) on hi lanes (o) — one exp+rcp
  float gBc = fmaxf(fminf(gB, 15.f), -15.f);
  float arg = lo ? (2.f * gBc) : (-gB);
  float eB = __expf(arg);
  float num = lo ? (eB - 1.f) : 1.f;
  float sB = num * __builtin_amdgcn_rcpf(eB + 1.f);

  float fv = swap_half(sA);                 // sig(f_j) -> lane j
  float ov = swap_half(sB);                 // sig(o_j) -> lane j
  c = fmaf(fv, c, sA * sB);                 // c = f*c + i*g   (valid lanes<32)
  float cc = fmaxf(fminf(c, 15.f), -15.f);
  float ec = __expf(2.f * cc);
  h = ov * (ec - 1.f) * __builtin_amdgcn_rcpf(ec + 1.f);  // h = o*tanh(c)
}

__global__ __launch_bounds__(64, 1)
__attribute__((amdgpu_waves_per_eu(1, 1)))
void lstm_fc_kernel(const float* __restrict__ Xp,
                    const float* __restrict__ w_hh,
                    const float* __restrict__ fc_w,
                    const float* __restrict__ fc_b,
                    float* __restrict__ out) {
  const int b = blockIdx.x;
  const int L = threadIdx.x;
  const bool lo = (L < 32);

  // weights: rows L and L+64 of w_hh packed as float2 per k
  float2v w2[32];
  {
    const float4* rA = (const float4*)(w_hh + L * 32);
    const float4* rB = (const float4*)(w_hh + (L + 64) * 32);
#pragma unroll
    for (int q = 0; q < 8; q++) {
      float4 a4 = rA[q], b4 = rB[q];
      w2[4 * q + 0] = (float2v){a4.x, b4.x};
      w2[4 * q + 1] = (float2v){a4.y, b4.y};
      w2[4 * q + 2] = (float2v){a4.z, b4.z};
      w2[4 * q + 3] = (float2v){a4.w, b4.w};
    }
  }

  const float* xp = Xp + (size_t)b * 512 * 128;
  float h = 0.f, c = 0.f;

  // 4-deep prefetch: one float2 (gates L, L+64) per step
  float2v p2[4];
#pragma unroll
  for (int u = 0; u < 4; u++) p2[u] = *(const float2v*)&xp[u * 128 + 2 * L];

  for (int t0 = 0; t0 < 512; t0 += 4) {
    float2v c2[4];
#pragma unroll
    for (int u = 0; u < 4; u++) c2[u] = p2[u];
    if (t0 + 4 < 512) {
#pragma unroll
      for (int u = 0; u < 4; u++)
        p2[u] = *(const float2v*)&xp[(t0 + 4 + u) * 128 + 2 * L];
    }
#pragma unroll
    for (int u = 0; u < 4; u++) lstm_step(h, c, c2[u], w2, lo);
  }

  float v = lo ? h * fc_w[L & 31] : 0.f;
#pragma unroll
  for (int off = 32; off > 0; off >>= 1) v += __shfl_down(v, off);
  if (L == 0) out[b] = v + fc_b[0];
}

// ---------------- launch ----------------
extern "C" void kernel_launch(void* const* d_in, const int* in_sizes, int n_in,
                              void* d_out, int out_size, void* d_ws, size_t ws_size,
                              hipStream_t stream) {
  const float* x      = (const float*)d_in[0];  // [256,1024,21]
  const float* conv_w = (const float*)d_in[1];  // [64,78,3]
  const float* conv_b = (const float*)d_in[2];  // [64]
  const float* w_ih   = (const float*)d_in[3];  // [128,64]
  const float* w_hh   = (const float*)d_in[4];  // [128,32]
  const float* b_ih   = (const float*)d_in[5];  // [128]
  const float* b_hh   = (const float*)d_in[6];  // [128]
  const float* fc_w   = (const float*)d_in[7];  // [1,32]
  const float* fc_b   = (const float*)d_in[8];  // [1]
  float* out = (float*)d_out;                   // [256,1]

  char* wsb = (char*)d_ws;
  float* comb = (float*)wsb;                          // 256*78*1024*4 = 81,788,928 B
  float* Xp   = (float*)wsb;                          // aliases comb (dead after conv)
  float* y    = (float*)(wsb + 81788928);             // 256*512*64*4 = 33,554,432 B
  float* wT   = (float*)(wsb + 81788928 + 33554432);  // 78*3*64*4 = 59,904 B

  transpose_w_kernel<<<dim3(59), dim3(256), 0, stream>>>(conv_w, wT);
  features_kernel<<<dim3(1024), dim3(256), 0, stream>>>(x, comb);
  conv_pool_kernel<<<dim3(16, 256), dim3(256), 0, stream>>>(comb, wT, conv_b, y);
  proj_kernel<<<dim3(4096), dim3(256), 0, stream>>>(y, w_ih, b_ih, b_hh, Xp);
  lstm_fc_kernel<<<dim3(256), dim3(64), 0, stream>>>(Xp, w_hh, fc_w, fc_b, out);
}

// Round 7
// 304.130 us; speedup vs baseline: 1.8444x; 1.3112x over previous
//
#include <hip/hip_runtime.h>
#include <math.h>

typedef _Float16 half8 __attribute__((ext_vector_type(8)));
typedef float floatx16 __attribute__((ext_vector_type(16)));
typedef float float2v __attribute__((ext_vector_type(2)));

// ---------------- constants ----------------
constexpr float DLO[8] = {-0.010597401784997278f, 0.032883011666982945f, 0.030841381835986965f,
                          -0.18703481171888114f, -0.02798376941698385f, 0.6308807679295904f,
                          0.7148465705525415f, 0.23037781330885523f};
constexpr float DHI[8] = {-0.23037781330885523f, 0.7148465705525415f, -0.6308807679295904f,
                          -0.02798376941698385f, 0.18703481171888114f, 0.030841381835986965f,
                          -0.032883011666982945f, -0.010597401784997278f};

// cos/sin(2*pi*m/21), m=0..20
constexpr float CT21[21] = {
  1.0f,          0.95557281f,  0.82623877f,  0.62348980f,  0.36534102f,  0.07473009f,
  -0.22252093f, -0.5f,        -0.73305187f, -0.90096887f, -0.98883083f,
  -0.98883083f, -0.90096887f, -0.73305187f, -0.5f,        -0.22252093f,
  0.07473009f,   0.36534102f,  0.62348980f,  0.82623877f,  0.95557281f};
constexpr float ST21[21] = {
  0.0f,          0.29475517f,  0.56332006f,  0.78183148f,  0.93087375f,  0.99720380f,
  0.97492791f,   0.86602540f,  0.68017274f,  0.43388374f,  0.14904227f,
  -0.14904227f, -0.43388374f, -0.68017274f, -0.86602540f, -0.97492791f,
  -0.99720380f, -0.93087375f, -0.78183148f, -0.56332006f, -0.29475517f};

template<int N>
__device__ __forceinline__ void dwt_step(const float* in, float* a, float* d) {
  constexpr int NO = (N + 7) / 2;
#pragma unroll
  for (int i = 0; i < NO; i++) {
    float sa = 0.f, sd = 0.f;
#pragma unroll
    for (int j = 0; j < 8; j++) {
      int rel = 2 * i + j - 6;
      int idx = (rel < 0) ? (-rel - 1) : ((rel >= N) ? (2 * N - rel - 1) : rel);
      float v = in[idx];
      sa = fmaf(v, DLO[7 - j], sa);
      sd = fmaf(v, DHI[7 - j], sd);
    }
    a[i] = sa;
    d[i] = sd;
  }
}

// ---------------- kernel 1: features -> comb_t[b][s][88] fp16 (s-major, coalesced) ----------------
// c-rows: 0..20 x, 21..31 |rfft|, 32..38 cA4, 39..45 cD4, 46..53 cD3, 54..63 cD2,
// 64..77 cD1, 78..87 zero pad
__global__ __launch_bounds__(256) void features_kernel(const float* __restrict__ x,
                                                       _Float16* __restrict__ comb_t) {
  __shared__ float xl[256 * 21];
  const int tid = threadIdx.x;
  const int g0 = blockIdx.x * 256;
  for (int idx = tid; idx < 256 * 21; idx += 256) xl[idx] = x[g0 * 21 + idx];
  __syncthreads();

  float xx[21];
#pragma unroll
  for (int t = 0; t < 21; t++) xx[t] = xl[tid * 21 + t];

  __align__(16) _Float16 hrow[88];
#pragma unroll
  for (int i = 78; i < 88; i++) hrow[i] = (_Float16)0.f;

  // raw copy
#pragma unroll
  for (int t = 0; t < 21; t++) hrow[t] = (_Float16)xx[t];

  // 21-point DFT magnitudes (k = 0..10)
#pragma unroll
  for (int k = 0; k < 11; k++) {
    float re = 0.f, im = 0.f;
#pragma unroll
    for (int t = 0; t < 21; t++) {
      const int m = (k * t) % 21;
      re = fmaf(xx[t], CT21[m], re);
      im = fmaf(xx[t], ST21[m], im);
    }
    hrow[21 + k] = (_Float16)sqrtf(re * re + im * im);
  }

  // db4 wavedec, 4 levels
  float a1[14], d1[14];
  dwt_step<21>(xx, a1, d1);
#pragma unroll
  for (int i = 0; i < 14; i++) hrow[64 + i] = (_Float16)d1[i];
  float a2[10], d2[10];
  dwt_step<14>(a1, a2, d2);
#pragma unroll
  for (int i = 0; i < 10; i++) hrow[54 + i] = (_Float16)d2[i];
  float a3[8], d3[8];
  dwt_step<10>(a2, a3, d3);
#pragma unroll
  for (int i = 0; i < 8; i++) hrow[46 + i] = (_Float16)d3[i];
  float a4[7], d4[7];
  dwt_step<8>(a3, a4, d4);
#pragma unroll
  for (int i = 0; i < 7; i++) {
    hrow[32 + i] = (_Float16)a4[i];
    hrow[39 + i] = (_Float16)d4[i];
  }

  const size_t gid = (size_t)g0 + tid;
  uint4* dst = (uint4*)(comb_t + gid * 88);
  const uint4* srcv = (const uint4*)hrow;
#pragma unroll
  for (int i = 0; i < 11; i++) dst[i] = srcv[i];
}

// ---------------- kernel 0: weight prep: WbT[o][k], k = dk*80 + c, fp16, zero-padded ----------------
__global__ __launch_bounds__(256) void wprep_kernel(const float* __restrict__ cw,
                                                    _Float16* __restrict__ WbT) {
  int idx = blockIdx.x * 256 + threadIdx.x;  // 64*264 = 16896
  if (idx < 64 * 264) {
    int o = idx / 264, k = idx - o * 264;
    float v = 0.f;
    if (k < 240) {
      int dk = k / 80, c = k - dk * 80;
      if (c < 78) v = cw[o * 234 + c * 3 + dk];
    }
    WbT[idx] = (_Float16)v;
  }
}

// ---------------- kernel 2: conv as fp16 MFMA implicit GEMM + bias + relu + pool ----------------
// block: one b, 128 s-positions, all 64 o. 4 waves, each: m-tile 32 (s), 2 n-tiles of 32 (o).
// K = 240 (= 3 dk-sections of 80), 15 K-steps of 16. A[m][k] = comb_t[b][s0+m+dk-1][c].
__global__ __launch_bounds__(256, 2) void conv_mfma_kernel(const _Float16* __restrict__ comb_t,
                                                           const _Float16* __restrict__ WbT,
                                                           const float* __restrict__ cbias,
                                                           float* __restrict__ y) {
  __shared__ __align__(16) _Float16 At[130 * 88];   // rows j=0..129 <-> s = s0-1+j
  __shared__ __align__(16) _Float16 Bt[64 * 264];
  __shared__ float bl[64];

  const int tid = threadIdx.x;
  const int b = blockIdx.y;
  const int s0 = blockIdx.x * 128;

  // stage A: contiguous copy of comb_t rows s0-1 .. s0+128 (1430 x 16B chunks)
  {
    const uint4* src = (const uint4*)(comb_t + (size_t)((b << 10) + s0 - 1) * 88);
    uint4* dA = (uint4*)At;
#pragma unroll
    for (int i = 0; i < 6; i++) {
      int idx = i * 256 + tid;
      if (idx < 1430) dA[idx] = src[idx];
    }
    const uint4* ws = (const uint4*)WbT;
    uint4* dB = (uint4*)Bt;
#pragma unroll
    for (int i = 0; i < 9; i++) {
      int idx = i * 256 + tid;
      if (idx < 2112) dB[idx] = ws[idx];
    }
  }
  if (tid < 64) bl[tid] = cbias[tid];
  __syncthreads();
  // zero out-of-range rows (s=-1 for first block, s=1024 for last) AFTER staging
  if (s0 == 0 && tid < 88) At[tid] = (_Float16)0.f;
  if (s0 == 896 && tid < 88) At[129 * 88 + tid] = (_Float16)0.f;
  __syncthreads();

  const int wave = tid >> 6, lane = tid & 63;
  const int ml = lane & 31;      // m within tile (A) / n within tile (B/C col)
  const int kg = lane >> 5;      // k-group (8 elems)
  const int am = wave * 32 + ml;

  floatx16 acc0 = {};
  floatx16 acc1 = {};

#pragma unroll
  for (int ks = 0; ks < 15; ks++) {
    const int kb = ks * 16 + kg * 8;                      // same dk for both kg (80 % 16 == 0)
    const int dk = (kb >= 160) ? 2 : ((kb >= 80) ? 1 : 0);
    const int c = kb - dk * 80;
    half8 av = *(const half8*)&At[(am + dk) * 88 + c];
    half8 bv0 = *(const half8*)&Bt[ml * 264 + kb];
    half8 bv1 = *(const half8*)&Bt[(32 + ml) * 264 + kb];
    acc0 = __builtin_amdgcn_mfma_f32_32x32x16_f16(av, bv0, acc0, 0, 0, 0);
    acc1 = __builtin_amdgcn_mfma_f32_32x32x16_f16(av, bv1, acc1, 0, 0, 0);
  }

  // epilogue: C row = (reg&3) + 8*(reg>>2) + 4*kg, col = ml. pool pairs = adjacent regs.
  const float b0 = bl[ml], b1 = bl[32 + ml];
  const int tB = (s0 >> 1) + wave * 16 + (kg << 1);
  float* yb = y + (size_t)b * 512 * 64;
#pragma unroll
  for (int p = 0; p < 8; p++) {
    const int toff = (p & 1) + ((p >> 1) << 2);           // {0,1,4,5,8,9,12,13}
    const int t = tB + toff;
    float v0 = fmaxf(fmaxf(acc0[2 * p], acc0[2 * p + 1]) + b0, 0.f);
    float v1 = fmaxf(fmaxf(acc1[2 * p], acc1[2 * p + 1]) + b1, 0.f);
    yb[(size_t)t * 64 + ml] = v0;
    yb[(size_t)t * 64 + 32 + ml] = v1;
  }
}

// ---------------- kernel 3: X_proj = y @ w_ih^T + (b_ih + b_hh), interleaved gate layout ----------------
__global__ __launch_bounds__(256) void proj_kernel(const float* __restrict__ y,
                                                   const float* __restrict__ w_ih,
                                                   const float* __restrict__ b_ih,
                                                   const float* __restrict__ b_hh,
                                                   float* __restrict__ Xp) {
  __shared__ __align__(16) float yl[32 * 68];
  __shared__ __align__(16) float wl[128 * 68];
  __shared__ float bl[128];

  const int tid = threadIdx.x;
  const int R0 = blockIdx.x * 32;

  for (int idx = tid; idx < 2048; idx += 256) {
    int r = idx >> 6, j = idx & 63;
    yl[r * 68 + j] = y[R0 * 64 + idx];
  }
  for (int idx = tid; idx < 8192; idx += 256) {
    int g = idx >> 6, j = idx & 63;
    wl[g * 68 + j] = w_ih[idx];
  }
  if (tid < 128) bl[tid] = b_ih[tid] + b_hh[tid];
  __syncthreads();

  const int rq = tid & 7, gq = tid >> 3;
  const int r0 = rq * 4, g0 = gq * 4;
  float acc[4][4];
#pragma unroll
  for (int i = 0; i < 4; i++)
#pragma unroll
    for (int n = 0; n < 4; n++) acc[i][n] = 0.f;

  for (int jq = 0; jq < 16; jq++) {
    const int j = jq * 4;
    float4 yv[4], wv[4];
#pragma unroll
    for (int i = 0; i < 4; i++) yv[i] = *(const float4*)&yl[(r0 + i) * 68 + j];
#pragma unroll
    for (int n = 0; n < 4; n++) wv[n] = *(const float4*)&wl[(g0 + n) * 68 + j];
#pragma unroll
    for (int i = 0; i < 4; i++)
#pragma unroll
      for (int n = 0; n < 4; n++) {
        acc[i][n] = fmaf(yv[i].x, wv[n].x, acc[i][n]);
        acc[i][n] = fmaf(yv[i].y, wv[n].y, acc[i][n]);
        acc[i][n] = fmaf(yv[i].z, wv[n].z, acc[i][n]);
        acc[i][n] = fmaf(yv[i].w, wv[n].w, acc[i][n]);
      }
  }

#pragma unroll
  for (int i = 0; i < 4; i++) {
#pragma unroll
    for (int n = 0; n < 4; n++) {
      const int g = g0 + n;
      const int p = ((g & 63) << 1) | (g >> 6);  // interleaved position
      Xp[(R0 + r0 + i) * 128 + p] = acc[i][n] + bl[g];
    }
  }
}

// ---------------- kernel 4: LSTM recurrence + fc (unchanged from R6) ----------------
__device__ __forceinline__ float bcast_lane(float v, int k) {
  return __uint_as_float(__builtin_amdgcn_readlane(__float_as_uint(v), k));
}

#if __has_builtin(__builtin_amdgcn_permlane32_swap)
__device__ __forceinline__ float swap_half(float x) {
  auto r = __builtin_amdgcn_permlane32_swap(__float_as_uint(x), __float_as_uint(x),
                                            false, false);
  return __uint_as_float(r[1]);
}
#else
__device__ __forceinline__ float swap_half(float x) { return __shfl_down(x, 32); }
#endif

__device__ __forceinline__ void lstm_step(float& h, float& c, float2v xg,
                                          const float2v* __restrict__ w2, bool lo) {
  float hs[32];
#pragma unroll
  for (int k = 0; k < 32; k++) hs[k] = bcast_lane(h, k);

  float2v a0 = xg, a1 = (float2v){0.f, 0.f};
#pragma unroll
  for (int k = 0; k < 32; k += 2) {
    float2v h0 = (float2v){hs[k], hs[k]};
    float2v h1 = (float2v){hs[k + 1], hs[k + 1]};
    a0 = __builtin_elementwise_fma(h0, w2[k], a0);
    a1 = __builtin_elementwise_fma(h1, w2[k + 1], a1);
  }
  float2v g2 = a0 + a1;
  float gA = g2.x, gB = g2.y;

  float eA = __expf(-gA);
  float sA = __builtin_amdgcn_rcpf(1.0f + eA);

  float gBc = fmaxf(fminf(gB, 15.f), -15.f);
  float arg = lo ? (2.f * gBc) : (-gB);
  float eB = __expf(arg);
  float num = lo ? (eB - 1.f) : 1.f;
  float sB = num * __builtin_amdgcn_rcpf(eB + 1.f);

  float fv = swap_half(sA);
  float ov = swap_half(sB);
  c = fmaf(fv, c, sA * sB);
  float cc = fmaxf(fminf(c, 15.f), -15.f);
  float ec = __expf(2.f * cc);
  h = ov * (ec - 1.f) * __builtin_amdgcn_rcpf(ec + 1.f);
}

__global__ __launch_bounds__(64, 1)
__attribute__((amdgpu_waves_per_eu(1, 1)))
void lstm_fc_kernel(const float* __restrict__ Xp,
                    const float* __restrict__ w_hh,
                    const float* __restrict__ fc_w,
                    const float* __restrict__ fc_b,
                    float* __restrict__ out) {
  const int b = blockIdx.x;
  const int L = threadIdx.x;
  const bool lo = (L < 32);

  float2v w2[32];
  {
    const float4* rA = (const float4*)(w_hh + L * 32);
    const float4* rB = (const float4*)(w_hh + (L + 64) * 32);
#pragma unroll
    for (int q = 0; q < 8; q++) {
      float4 a4 = rA[q], b4 = rB[q];
      w2[4 * q + 0] = (float2v){a4.x, b4.x};
      w2[4 * q + 1] = (float2v){a4.y, b4.y};
      w2[4 * q + 2] = (float2v){a4.z, b4.z};
      w2[4 * q + 3] = (float2v){a4.w, b4.w};
    }
  }

  const float* xp = Xp + (size_t)b * 512 * 128;
  float h = 0.f, c = 0.f;

  float2v p2[4];
#pragma unroll
  for (int u = 0; u < 4; u++) p2[u] = *(const float2v*)&xp[u * 128 + 2 * L];

  for (int t0 = 0; t0 < 512; t0 += 4) {
    float2v c2[4];
#pragma unroll
    for (int u = 0; u < 4; u++) c2[u] = p2[u];
    if (t0 + 4 < 512) {
#pragma unroll
      for (int u = 0; u < 4; u++)
        p2[u] = *(const float2v*)&xp[(t0 + 4 + u) * 128 + 2 * L];
    }
#pragma unroll
    for (int u = 0; u < 4; u++) lstm_step(h, c, c2[u], w2, lo);
  }

  float v = lo ? h * fc_w[L & 31] : 0.f;
#pragma unroll
  for (int off = 32; off > 0; off >>= 1) v += __shfl_down(v, off);
  if (L == 0) out[b] = v + fc_b[0];
}

// ---------------- launch ----------------
extern "C" void kernel_launch(void* const* d_in, const int* in_sizes, int n_in,
                              void* d_out, int out_size, void* d_ws, size_t ws_size,
                              hipStream_t stream) {
  const float* x      = (const float*)d_in[0];  // [256,1024,21]
  const float* conv_w = (const float*)d_in[1];  // [64,78,3]
  const float* conv_b = (const float*)d_in[2];  // [64]
  const float* w_ih   = (const float*)d_in[3];  // [128,64]
  const float* w_hh   = (const float*)d_in[4];  // [128,32]
  const float* b_ih   = (const float*)d_in[5];  // [128]
  const float* b_hh   = (const float*)d_in[6];  // [128]
  const float* fc_w   = (const float*)d_in[7];  // [1,32]
  const float* fc_b   = (const float*)d_in[8];  // [1]
  float* out = (float*)d_out;                   // [256,1]

  char* wsb = (char*)d_ws;
  // layout: [y 33,554,432][comb_t (46,137,344) / Xp (67,108,864) shared][WbT 33,792]
  float*     y      = (float*)wsb;
  _Float16*  comb_t = (_Float16*)(wsb + 33554432);
  float*     Xp     = (float*)(wsb + 33554432);
  _Float16*  WbT    = (_Float16*)(wsb + 33554432 + 67108864);

  wprep_kernel<<<dim3(66), dim3(256), 0, stream>>>(conv_w, WbT);
  features_kernel<<<dim3(1024), dim3(256), 0, stream>>>(x, comb_t);
  conv_mfma_kernel<<<dim3(8, 256), dim3(256), 0, stream>>>(comb_t, WbT, conv_b, y);
  proj_kernel<<<dim3(4096), dim3(256), 0, stream>>>(y, w_ih, b_ih, b_hh, Xp);
  lstm_fc_kernel<<<dim3(256), dim3(64), 0, stream>>>(Xp, w_hh, fc_w, fc_b, out);
}

// Round 9
// 249.834 us; speedup vs baseline: 2.2452x; 1.2173x over previous
//
#include <hip/hip_runtime.h>
#include <math.h>

typedef _Float16 half8 __attribute__((ext_vector_type(8)));
typedef float floatx16 __attribute__((ext_vector_type(16)));
typedef float float2v __attribute__((ext_vector_type(2)));

constexpr float L2E = 1.4426950408889634f;

// ---------------- constants ----------------
constexpr float DLO[8] = {-0.010597401784997278f, 0.032883011666982945f, 0.030841381835986965f,
                          -0.18703481171888114f, -0.02798376941698385f, 0.6308807679295904f,
                          0.7148465705525415f, 0.23037781330885523f};
constexpr float DHI[8] = {-0.23037781330885523f, 0.7148465705525415f, -0.6308807679295904f,
                          -0.02798376941698385f, 0.18703481171888114f, 0.030841381835986965f,
                          -0.032883011666982945f, -0.010597401784997278f};

constexpr float CT21[21] = {
  1.0f,          0.95557281f,  0.82623877f,  0.62348980f,  0.36534102f,  0.07473009f,
  -0.22252093f, -0.5f,        -0.73305187f, -0.90096887f, -0.98883083f,
  -0.98883083f, -0.90096887f, -0.73305187f, -0.5f,        -0.22252093f,
  0.07473009f,   0.36534102f,  0.62348980f,  0.82623877f,  0.95557281f};
constexpr float ST21[21] = {
  0.0f,          0.29475517f,  0.56332006f,  0.78183148f,  0.93087375f,  0.99720380f,
  0.97492791f,   0.86602540f,  0.68017274f,  0.43388374f,  0.14904227f,
  -0.14904227f, -0.43388374f, -0.68017274f, -0.86602540f, -0.97492791f,
  -0.99720380f, -0.93087375f, -0.78183148f, -0.56332006f, -0.29475517f};

template<int N>
__device__ __forceinline__ void dwt_step(const float* in, float* a, float* d) {
  constexpr int NO = (N + 7) / 2;
#pragma unroll
  for (int i = 0; i < NO; i++) {
    float sa = 0.f, sd = 0.f;
#pragma unroll
    for (int j = 0; j < 8; j++) {
      int rel = 2 * i + j - 6;
      int idx = (rel < 0) ? (-rel - 1) : ((rel >= N) ? (2 * N - rel - 1) : rel);
      float v = in[idx];
      sa = fmaf(v, DLO[7 - j], sa);
      sd = fmaf(v, DHI[7 - j], sd);
    }
    a[i] = sa;
    d[i] = sd;
  }
}

// ---------------- kernel 1: features -> comb_t[b][s][88] fp16 ----------------
__global__ __launch_bounds__(256) void features_kernel(const float* __restrict__ x,
                                                       _Float16* __restrict__ comb_t) {
  __shared__ float xl[256 * 21];
  const int tid = threadIdx.x;
  const int g0 = blockIdx.x * 256;
  for (int idx = tid; idx < 256 * 21; idx += 256) xl[idx] = x[g0 * 21 + idx];
  __syncthreads();

  float xx[21];
#pragma unroll
  for (int t = 0; t < 21; t++) xx[t] = xl[tid * 21 + t];

  __align__(16) _Float16 hrow[88];
#pragma unroll
  for (int i = 78; i < 88; i++) hrow[i] = (_Float16)0.f;

#pragma unroll
  for (int t = 0; t < 21; t++) hrow[t] = (_Float16)xx[t];

#pragma unroll
  for (int k = 0; k < 11; k++) {
    float re = 0.f, im = 0.f;
#pragma unroll
    for (int t = 0; t < 21; t++) {
      const int m = (k * t) % 21;
      re = fmaf(xx[t], CT21[m], re);
      im = fmaf(xx[t], ST21[m], im);
    }
    hrow[21 + k] = (_Float16)sqrtf(re * re + im * im);
  }

  float a1[14], d1[14];
  dwt_step<21>(xx, a1, d1);
#pragma unroll
  for (int i = 0; i < 14; i++) hrow[64 + i] = (_Float16)d1[i];
  float a2[10], d2[10];
  dwt_step<14>(a1, a2, d2);
#pragma unroll
  for (int i = 0; i < 10; i++) hrow[54 + i] = (_Float16)d2[i];
  float a3[8], d3[8];
  dwt_step<10>(a2, a3, d3);
#pragma unroll
  for (int i = 0; i < 8; i++) hrow[46 + i] = (_Float16)d3[i];
  float a4[7], d4[7];
  dwt_step<8>(a3, a4, d4);
#pragma unroll
  for (int i = 0; i < 7; i++) {
    hrow[32 + i] = (_Float16)a4[i];
    hrow[39 + i] = (_Float16)d4[i];
  }

  const size_t gid = (size_t)g0 + tid;
  uint4* dst = (uint4*)(comb_t + gid * 88);
  const uint4* srcv = (const uint4*)hrow;
#pragma unroll
  for (int i = 0; i < 11; i++) dst[i] = srcv[i];
}

// ---------------- kernel 0: weight prep ----------------
// WbT[o][k] conv weights (k = dk*80+c, 264-padded); wih16[g][64] = L2E*w_ih fp16;
// biasI[p(g)] = L2E*(b_ih+b_hh)  (Xp is produced pre-scaled by log2(e))
__global__ __launch_bounds__(256) void wprep_kernel(const float* __restrict__ cw,
                                                    const float* __restrict__ w_ih,
                                                    const float* __restrict__ b_ih,
                                                    const float* __restrict__ b_hh,
                                                    _Float16* __restrict__ WbT,
                                                    _Float16* __restrict__ wih16,
                                                    float* __restrict__ biasI) {
  int idx = blockIdx.x * 256 + threadIdx.x;
  if (idx < 64 * 264) {
    int o = idx / 264, k = idx - o * 264;
    float v = 0.f;
    if (k < 240) {
      int dk = k / 80, c = k - dk * 80;
      if (c < 78) v = cw[o * 234 + c * 3 + dk];
    }
    WbT[idx] = (_Float16)v;
  } else if (idx < 16896 + 8192) {
    int j = idx - 16896;
    wih16[j] = (_Float16)(L2E * w_ih[j]);
  } else if (idx < 16896 + 8192 + 128) {
    int g = idx - 16896 - 8192;
    int p = ((g & 63) << 1) | (g >> 6);
    biasI[p] = L2E * (b_ih[g] + b_hh[g]);
  }
}

// ---------------- kernel 2: fused conv(MFMA)+pool+proj(MFMA) -> Xp ----------------
// block: one b, 128 s (=64 t), all 64 ch. Phase A: conv implicit GEMM (K=240).
// Phase B: pooled y tile (64x64 fp16) -> LDS; stage w_ihT. Phase C: proj MFMA
// (M=64,N=128,K=64), Xp tile staged in LDS, coalesced fp32 writeout + bias.
// NOTE: comb_t MUST have >=176 mapped bytes before it (b=0,s0=0 stages row s=-1)
// and >=176 after (b=255,s0=896 stages row s=1024); launch layout guarantees both.
__global__ __launch_bounds__(256, 2) void conv_proj_kernel(const _Float16* __restrict__ comb_t,
                                                           const _Float16* __restrict__ WbT,
                                                           const float* __restrict__ cbias,
                                                           const _Float16* __restrict__ wih16,
                                                           const float* __restrict__ biasI,
                                                           float* __restrict__ Xp) {
  // LDS union: phaseA At[0,22880) Bt[22880,56672)
  //            phaseB yt[0,9216) wl[9216,27648) biasl[27648,28160) Xpt[28160,60928)
  //            bl [60928,61184) (live whole kernel)
  __shared__ __align__(16) char smem[61184];
  _Float16* At = (_Float16*)smem;
  _Float16* Bt = (_Float16*)(smem + 22880);
  _Float16* yt = (_Float16*)smem;
  _Float16* wl = (_Float16*)(smem + 9216);
  float* biasl = (float*)(smem + 27648);
  float* Xpt   = (float*)(smem + 28160);
  float* bl    = (float*)(smem + 60928);

  const int tid = threadIdx.x;
  const int b = blockIdx.y;
  const int s0 = blockIdx.x * 128;
  const int T0 = blockIdx.x * 64;

  // ---- phase A: stage conv inputs ----
  {
    const uint4* src = (const uint4*)(comb_t + (size_t)((b << 10) + s0 - 1) * 88);
    uint4* dA = (uint4*)At;
#pragma unroll
    for (int i = 0; i < 6; i++) {
      int idx = i * 256 + tid;
      if (idx < 1430) dA[idx] = src[idx];
    }
    const uint4* ws = (const uint4*)WbT;
    uint4* dB = (uint4*)Bt;
#pragma unroll
    for (int i = 0; i < 9; i++) {
      int idx = i * 256 + tid;
      if (idx < 2112) dB[idx] = ws[idx];
    }
  }
  if (tid < 64) bl[tid] = cbias[tid];
  __syncthreads();
  if (s0 == 0 && tid < 88) At[tid] = (_Float16)0.f;
  if (s0 == 896 && tid < 88) At[129 * 88 + tid] = (_Float16)0.f;
  __syncthreads();

  const int wave = tid >> 6, lane = tid & 63;
  const int ml = lane & 31;
  const int kg = lane >> 5;
  const int am = wave * 32 + ml;

  floatx16 acc0 = {};
  floatx16 acc1 = {};
#pragma unroll
  for (int ks = 0; ks < 15; ks++) {
    const int kb = ks * 16 + kg * 8;
    const int dk = (kb >= 160) ? 2 : ((kb >= 80) ? 1 : 0);
    const int c = kb - dk * 80;
    half8 av = *(const half8*)&At[(am + dk) * 88 + c];
    half8 bv0 = *(const half8*)&Bt[ml * 264 + kb];
    half8 bv1 = *(const half8*)&Bt[(32 + ml) * 264 + kb];
    acc0 = __builtin_amdgcn_mfma_f32_32x32x16_f16(av, bv0, acc0, 0, 0, 0);
    acc1 = __builtin_amdgcn_mfma_f32_32x32x16_f16(av, bv1, acc1, 0, 0, 0);
  }

  // pooled+bias+relu into registers (C layout: row=(reg&3)+8*(reg>>2)+4*kg, col=ml)
  const float b0 = bl[ml], b1 = bl[32 + ml];
  float v0s[8], v1s[8];
#pragma unroll
  for (int p = 0; p < 8; p++) {
    v0s[p] = fmaxf(fmaxf(acc0[2 * p], acc0[2 * p + 1]) + b0, 0.f);
    v1s[p] = fmaxf(fmaxf(acc1[2 * p], acc1[2 * p + 1]) + b1, 0.f);
  }

  __syncthreads();  // all conv LDS reads done before repurposing

  // ---- phase B: y tile (fp16, stride 72) + w_ihT + bias ----
#pragma unroll
  for (int p = 0; p < 8; p++) {
    const int toff = (p & 1) + ((p >> 1) << 2);  // {0,1,4,5,8,9,12,13}
    const int t = wave * 16 + (kg << 1) + toff;
    yt[t * 72 + ml] = (_Float16)v0s[p];
    yt[t * 72 + 32 + ml] = (_Float16)v1s[p];
  }
  for (int i = tid; i < 2048; i += 256) {
    int g = i >> 4, c4 = i & 15;
    *(uint2*)(wl + g * 72 + c4 * 4) = *(const uint2*)(wih16 + g * 64 + c4 * 4);
  }
  if (tid < 128) biasl[tid] = biasI[tid];
  __syncthreads();

  // ---- phase C: proj MFMA. wave w: m-tile = w&1, n-tiles = (w>>1)*2 + {0,1} ----
  const int tm = wave & 1, tn0 = (wave >> 1) * 2;
  floatx16 pa0 = {};
  floatx16 pa1 = {};
#pragma unroll
  for (int kq = 0; kq < 4; kq++) {
    const int k0 = kq * 16 + kg * 8;
    half8 av = *(const half8*)&yt[(tm * 32 + ml) * 72 + k0];
    half8 bv0 = *(const half8*)&wl[(tn0 * 32 + ml) * 72 + k0];
    half8 bv1 = *(const half8*)&wl[((tn0 + 1) * 32 + ml) * 72 + k0];
    pa0 = __builtin_amdgcn_mfma_f32_32x32x16_f16(av, bv0, pa0, 0, 0, 0);
    pa1 = __builtin_amdgcn_mfma_f32_32x32x16_f16(av, bv1, pa1, 0, 0, 0);
  }

  // scatter to LDS tile (interleaved gate layout), 2-way bank pattern = free
  {
    const int g0i = tn0 * 32 + ml;
    const int p0 = ((g0i & 63) << 1) | (g0i >> 6);
    const int g1i = (tn0 + 1) * 32 + ml;
    const int p1 = ((g1i & 63) << 1) | (g1i >> 6);
#pragma unroll
    for (int reg = 0; reg < 16; reg++) {
      const int row = (reg & 3) + 8 * (reg >> 2) + 4 * kg;
      const int m = tm * 32 + row;
      Xpt[m * 128 + p0] = pa0[reg];
      Xpt[m * 128 + p1] = pa1[reg];
    }
  }
  __syncthreads();

  // ---- coalesced writeout + bias ----
  float* xpg = Xp + ((size_t)b * 512 + T0) * 128;
  for (int i = tid; i < 2048; i += 256) {
    const int r = i >> 5, c4 = (i & 31) << 2;
    float4 v = *(float4*)&Xpt[r * 128 + c4];
    float4 bb = *(float4*)&biasl[c4];
    v.x += bb.x; v.y += bb.y; v.z += bb.z; v.w += bb.w;
    *(float4*)&xpg[r * 128 + c4] = v;
  }
}

// ---------------- kernel 3: LSTM recurrence + fc ----------------
// Xp/w_hh pre-scaled by log2(e) -> raw v_exp (no argument muls); inf-safe
// tanh/sigmoid via 1-2*rcp / rcp (clamps dropped); h = fma(-2ov, rc, ov).
__device__ __forceinline__ float bcast_lane(float v, int k) {
  return __uint_as_float(__builtin_amdgcn_readlane(__float_as_uint(v), k));
}

#if __has_builtin(__builtin_amdgcn_exp2f)
#define EXP2F __builtin_amdgcn_exp2f
#else
#define EXP2F exp2f
#endif

#if __has_builtin(__builtin_amdgcn_permlane32_swap)
__device__ __forceinline__ float swap_half(float x) {
  auto r = __builtin_amdgcn_permlane32_swap(__float_as_uint(x), __float_as_uint(x),
                                            false, false);
  return __uint_as_float(r[1]);
}
#else
__device__ __forceinline__ float swap_half(float x) { return __shfl_down(x, 32); }
#endif

__device__ __forceinline__ void lstm_step(float& h, float& c, float2v xg,
                                          const float2v* __restrict__ w2, bool lo) {
  float hs[32];
#pragma unroll
  for (int k = 0; k < 32; k++) hs[k] = bcast_lane(h, k);

  float2v a0 = xg, a1 = (float2v){0.f, 0.f};
#pragma unroll
  for (int k = 0; k < 32; k += 2) {
    float2v h0 = (float2v){hs[k], hs[k]};
    float2v h1 = (float2v){hs[k + 1], hs[k + 1]};
    a0 = __builtin_elementwise_fma(h0, w2[k], a0);
    a1 = __builtin_elementwise_fma(h1, w2[k + 1], a1);
  }
  float2v g2 = a0 + a1;
  const float gA = g2.x, gB = g2.y;     // pre-scaled by log2e

  // sA = sigmoid(gA/L2E) on all lanes (i for lo, f for hi); inf-safe
  float sA = __builtin_amdgcn_rcpf(1.0f + EXP2F(-gA));

  // sB: lo -> tanh = 1-2*rcp(exp2(2gB)+1); hi -> sigmoid = rcp(exp2(-gB)+1)
  float argB = lo ? (gB + gB) : (-gB);
  float rB = __builtin_amdgcn_rcpf(EXP2F(argB) + 1.0f);
  float sB = lo ? fmaf(-2.f, rB, 1.f) : rB;

  float fv = swap_half(sA);
  float ov = swap_half(sB);
  c = fmaf(fv, c, sA * sB);             // c in true units (lanes<32)
  float rc = __builtin_amdgcn_rcpf(EXP2F(c * (2.f * L2E)) + 1.0f);
  float ov2 = ov + ov;
  h = fmaf(-ov2, rc, ov);               // h = ov * tanh(c)
}

__global__ __launch_bounds__(64, 1)
__attribute__((amdgpu_waves_per_eu(1, 1)))
void lstm_fc_kernel(const float* __restrict__ Xp,
                    const float* __restrict__ w_hh,
                    const float* __restrict__ fc_w,
                    const float* __restrict__ fc_b,
                    float* __restrict__ out) {
  const int b = blockIdx.x;
  const int L = threadIdx.x;
  const bool lo = (L < 32);

  float2v w2[32];   // rows L and L+64 of w_hh, scaled by log2e
  {
    const float4* rA = (const float4*)(w_hh + L * 32);
    const float4* rB = (const float4*)(w_hh + (L + 64) * 32);
#pragma unroll
    for (int q = 0; q < 8; q++) {
      float4 a4 = rA[q], b4 = rB[q];
      w2[4 * q + 0] = (float2v){L2E * a4.x, L2E * b4.x};
      w2[4 * q + 1] = (float2v){L2E * a4.y, L2E * b4.y};
      w2[4 * q + 2] = (float2v){L2E * a4.z, L2E * b4.z};
      w2[4 * q + 3] = (float2v){L2E * a4.w, L2E * b4.w};
    }
  }

  const float* xp = Xp + (size_t)b * 512 * 128;
  float h = 0.f, c = 0.f;

  float2v p2[4];
#pragma unroll
  for (int u = 0; u < 4; u++) p2[u] = *(const float2v*)&xp[u * 128 + 2 * L];

  for (int t0 = 0; t0 < 512; t0 += 4) {
    float2v c2[4];
#pragma unroll
    for (int u = 0; u < 4; u++) c2[u] = p2[u];
    if (t0 + 4 < 512) {
#pragma unroll
      for (int u = 0; u < 4; u++)
        p2[u] = *(const float2v*)&xp[(t0 + 4 + u) * 128 + 2 * L];
    }
#pragma unroll
    for (int u = 0; u < 4; u++) lstm_step(h, c, c2[u], w2, lo);
  }

  float v = lo ? h * fc_w[L & 31] : 0.f;
#pragma unroll
  for (int off = 32; off > 0; off >>= 1) v += __shfl_down(v, off);
  if (L == 0) out[b] = v + fc_b[0];
}

// ---------------- launch ----------------
extern "C" void kernel_launch(void* const* d_in, const int* in_sizes, int n_in,
                              void* d_out, int out_size, void* d_ws, size_t ws_size,
                              hipStream_t stream) {
  const float* x      = (const float*)d_in[0];  // [256,1024,21]
  const float* conv_w = (const float*)d_in[1];  // [64,78,3]
  const float* conv_b = (const float*)d_in[2];  // [64]
  const float* w_ih   = (const float*)d_in[3];  // [128,64]
  const float* w_hh   = (const float*)d_in[4];  // [128,32]
  const float* b_ih   = (const float*)d_in[5];  // [128]
  const float* b_hh   = (const float*)d_in[6];  // [128]
  const float* fc_w   = (const float*)d_in[7];  // [1,32]
  const float* fc_b   = (const float*)d_in[8];  // [1]
  float* out = (float*)d_out;                   // [256,1]

  char* wsb = (char*)d_ws;
  // [pad 256][comb_t 46,137,344][Xp 67,108,864][WbT 33,792][wih16 16,384][biasI 512]
  // pad: conv_proj stages row s=-1 for the first block (reads comb_t - 176 B);
  // the pad keeps that inside d_ws. Total 113,297,408 B (< R1's 115.4 MB usage).
  _Float16* comb_t = (_Float16*)(wsb + 256);
  float*    Xp     = (float*)(wsb + 256 + 46137344);
  _Float16* WbT    = (_Float16*)(wsb + 256 + 46137344 + 67108864);
  _Float16* wih16  = (_Float16*)(wsb + 256 + 46137344 + 67108864 + 33792);
  float*    biasI  = (float*)(wsb + 256 + 46137344 + 67108864 + 33792 + 16384);

  wprep_kernel<<<dim3(99), dim3(256), 0, stream>>>(conv_w, w_ih, b_ih, b_hh,
                                                   WbT, wih16, biasI);
  features_kernel<<<dim3(1024), dim3(256), 0, stream>>>(x, comb_t);
  conv_proj_kernel<<<dim3(8, 256), dim3(256), 0, stream>>>(comb_t, WbT, conv_b,
                                                           wih16, biasI, Xp);
  lstm_fc_kernel<<<dim3(256), dim3(64), 0, stream>>>(Xp, w_hh, fc_w, fc_b, out);
}